// Round 4
// baseline (894.244 us; speedup 1.0000x reference)
//
#include <hip/hip_runtime.h>
#include <hip/hip_bf16.h>

#define NN 100000
#define EE 1600000
#define H  32
#define EIN 3
#define EH 32
#define EOUT 32

// ---------------------------------------------------------------------------
// CSR build: cnt/cursor zero -> histogram(dst) -> scan(ptr) + dis -> fill adj
// ---------------------------------------------------------------------------
__global__ void csr_init_kernel(int* __restrict__ cnt, int* __restrict__ cursor) {
    int i = blockIdx.x * blockDim.x + threadIdx.x;
    if (i < NN) { cnt[i] = 0; cursor[i] = 0; }
}

__global__ void csr_hist_kernel(const int* __restrict__ ei, int* __restrict__ cnt) {
    int e = blockIdx.x * blockDim.x + threadIdx.x;
    if (e < EE) atomicAdd(&cnt[ei[EE + e]], 1);
}

// single-block exclusive scan of cnt[0..NN) -> ptr, plus dis = 1/sqrt(deg+1)
__global__ void csr_scan_kernel(const int* __restrict__ cnt, int* __restrict__ ptr,
                                float* __restrict__ dis) {
    const int T = 1024;
    const int chunk = (NN + T - 1) / T;   // 98
    int tid = threadIdx.x;
    int start = tid * chunk;
    int end = min(start + chunk, NN);

    int sum = 0;
    for (int i = start; i < end; ++i) sum += cnt[i];

    __shared__ int part[T];
    part[tid] = sum;
    __syncthreads();
    for (int off = 1; off < T; off <<= 1) {
        int v = (tid >= off) ? part[tid - off] : 0;
        __syncthreads();
        part[tid] += v;
        __syncthreads();
    }
    int prefix = (tid == 0) ? 0 : part[tid - 1];

    for (int i = start; i < end; ++i) {
        ptr[i] = prefix;
        int c = cnt[i];
        prefix += c;
        dis[i] = 1.0f / sqrtf((float)(c + 1));
    }
    if (end == NN) ptr[NN] = prefix;   // benign multi-writer: all write EE
}

__global__ void csr_fill_kernel(const int* __restrict__ ei, const int* __restrict__ ptr,
                                int* __restrict__ cursor, int* __restrict__ adj) {
    int e = blockIdx.x * blockDim.x + threadIdx.x;
    if (e >= EE) return;
    int s = ei[e];
    int d = ei[EE + e];
    int pos = ptr[d] + atomicAdd(&cursor[d], 1);
    adj[pos] = s;
}

// ---------------------------------------------------------------------------
// Fused: node encoder MLP -> hws = dis[n] * (h_enc @ gW1)
// ---------------------------------------------------------------------------
__global__ void node_hws1_kernel(const float* __restrict__ x,
                                 const float* __restrict__ w1, const float* __restrict__ b1,
                                 const float* __restrict__ w2, const float* __restrict__ b2,
                                 const float* __restrict__ gW, const float* __restrict__ dis,
                                 float* __restrict__ hws) {
    __shared__ float sw1[2 * H];
    __shared__ float sb1[H];
    __shared__ float sw2[H * H];
    __shared__ float sb2[H];
    __shared__ float sgw[H * H];
    for (int i = threadIdx.x; i < 2 * H; i += blockDim.x) sw1[i] = w1[i];
    for (int i = threadIdx.x; i < H; i += blockDim.x) { sb1[i] = b1[i]; sb2[i] = b2[i]; }
    for (int i = threadIdx.x; i < H * H; i += blockDim.x) { sw2[i] = w2[i]; sgw[i] = gW[i]; }
    __syncthreads();

    int n = blockIdx.x * blockDim.x + threadIdx.x;
    if (n >= NN) return;

    float x0 = x[2 * n + 0];
    float x1 = x[2 * n + 1];

    float t[H];
#pragma unroll
    for (int j = 0; j < H; ++j)
        t[j] = fmaxf(fmaf(x1, sw1[H + j], fmaf(x0, sw1[j], sb1[j])), 0.0f);

    float henc[H];
#pragma unroll
    for (int c = 0; c < H; ++c) henc[c] = sb2[c];
#pragma unroll
    for (int j = 0; j < H; ++j) {
        float tj = t[j];
#pragma unroll
        for (int c = 0; c < H; ++c) henc[c] = fmaf(tj, sw2[j * H + c], henc[c]);
    }

    float o[H];
#pragma unroll
    for (int c = 0; c < H; ++c) o[c] = 0.0f;
#pragma unroll
    for (int j = 0; j < H; ++j) {
        float hj = henc[j];
#pragma unroll
        for (int c = 0; c < H; ++c) o[c] = fmaf(hj, sgw[j * H + c], o[c]);
    }

    float d = dis[n];
    float4* hp = reinterpret_cast<float4*>(hws + (size_t)n * H);
#pragma unroll
    for (int q = 0; q < H / 4; ++q)
        hp[q] = make_float4(o[4 * q + 0] * d, o[4 * q + 1] * d, o[4 * q + 2] * d, o[4 * q + 3] * d);
}

// ---------------------------------------------------------------------------
// Gather: acc[n][c] = dis[n] * (hws[n][c] + sum_{in-edges} hws[src][c])
// 32-lane group per node; lane = channel. adj loaded coalesced, shfl-broadcast.
// ---------------------------------------------------------------------------
__global__ void gcn_gather_kernel(const int* __restrict__ ptr, const int* __restrict__ adj,
                                  const float* __restrict__ hws, const float* __restrict__ dis,
                                  float* __restrict__ acc) {
    int lane = threadIdx.x & 31;
    int g = threadIdx.x >> 5;
    int n = blockIdx.x * (blockDim.x >> 5) + g;
    if (n >= NN) return;

    int rs = ptr[n];
    int re = ptr[n + 1];

    float a0 = hws[(size_t)n * H + lane];   // self-loop term
    float a1 = 0.0f;

    for (int base = rs; base < re; base += 32) {
        int cnt = re - base; if (cnt > 32) cnt = 32;
        int sv = adj[base + ((lane < cnt) ? lane : (cnt - 1))];
#pragma unroll 4
        for (int k = 0; k < cnt; k += 2) {
            int s0 = __shfl(sv, k, 32);
            a0 += hws[(size_t)s0 * H + lane];
            if (k + 1 < cnt) {
                int s1 = __shfl(sv, k + 1, 32);
                a1 += hws[(size_t)s1 * H + lane];
            }
        }
    }
    acc[(size_t)n * H + lane] = dis[n] * (a0 + a1);
}

// ---------------------------------------------------------------------------
// Fused: h1 = relu(acc + b_prev); hws = dis[n] * (h1 @ gW2)
// ---------------------------------------------------------------------------
__global__ void fin_hws2_kernel(const float* __restrict__ bprev, const float* __restrict__ gW,
                                const float* __restrict__ dis,
                                const float* __restrict__ acc, float* __restrict__ hws) {
    __shared__ float sgw[H * H];
    __shared__ float sb[H];
    for (int i = threadIdx.x; i < H * H; i += blockDim.x) sgw[i] = gW[i];
    for (int i = threadIdx.x; i < H; i += blockDim.x) sb[i] = bprev[i];
    __syncthreads();

    int n = blockIdx.x * blockDim.x + threadIdx.x;
    if (n >= NN) return;

    float hv[H];
    const float4* ap = reinterpret_cast<const float4*>(acc + (size_t)n * H);
#pragma unroll
    for (int q = 0; q < H / 4; ++q) {
        float4 v = ap[q];
        hv[4 * q + 0] = fmaxf(v.x + sb[4 * q + 0], 0.0f);
        hv[4 * q + 1] = fmaxf(v.y + sb[4 * q + 1], 0.0f);
        hv[4 * q + 2] = fmaxf(v.z + sb[4 * q + 2], 0.0f);
        hv[4 * q + 3] = fmaxf(v.w + sb[4 * q + 3], 0.0f);
    }

    float o[H];
#pragma unroll
    for (int c = 0; c < H; ++c) o[c] = 0.0f;
#pragma unroll
    for (int j = 0; j < H; ++j) {
        float hj = hv[j];
#pragma unroll
        for (int c = 0; c < H; ++c) o[c] = fmaf(hj, sgw[j * H + c], o[c]);
    }

    float d = dis[n];
    float4* hp = reinterpret_cast<float4*>(hws + (size_t)n * H);
#pragma unroll
    for (int q = 0; q < H / 4; ++q)
        hp[q] = make_float4(o[4 * q + 0] * d, o[4 * q + 1] * d, o[4 * q + 2] * d, o[4 * q + 3] * d);
}

// ---------------------------------------------------------------------------
// Fused: h = relu(acc + gb2) -> d_out ; A = h@eW1[0:32]+eb1 ; Bv = h@eW1[32:64]
// ---------------------------------------------------------------------------
__global__ void fin_ab_kernel(const float* __restrict__ acc, const float* __restrict__ gb,
                              const float* __restrict__ ew1, const float* __restrict__ eb1,
                              float* __restrict__ hout,
                              float* __restrict__ A, float* __restrict__ Bv) {
    __shared__ float sws[H * EH];   // rows 0..31 of ew1
    __shared__ float swd[H * EH];   // rows 32..63 of ew1
    __shared__ float sgb[H];
    __shared__ float seb[EH];
    for (int i = threadIdx.x; i < H * EH; i += blockDim.x) {
        sws[i] = ew1[i];
        swd[i] = ew1[H * EH + i];
    }
    for (int i = threadIdx.x; i < H; i += blockDim.x) sgb[i] = gb[i];
    for (int i = threadIdx.x; i < EH; i += blockDim.x) seb[i] = eb1[i];
    __syncthreads();

    int n = blockIdx.x * blockDim.x + threadIdx.x;
    if (n >= NN) return;

    float hv[H];
    const float4* ap = reinterpret_cast<const float4*>(acc + (size_t)n * H);
#pragma unroll
    for (int q = 0; q < H / 4; ++q) {
        float4 v = ap[q];
        hv[4 * q + 0] = fmaxf(v.x + sgb[4 * q + 0], 0.0f);
        hv[4 * q + 1] = fmaxf(v.y + sgb[4 * q + 1], 0.0f);
        hv[4 * q + 2] = fmaxf(v.z + sgb[4 * q + 2], 0.0f);
        hv[4 * q + 3] = fmaxf(v.w + sgb[4 * q + 3], 0.0f);
    }

    float av[EH], bv[EH];
#pragma unroll
    for (int c = 0; c < EH; ++c) { av[c] = seb[c]; bv[c] = 0.0f; }
#pragma unroll
    for (int j = 0; j < H; ++j) {
        float hj = hv[j];
#pragma unroll
        for (int c = 0; c < EH; ++c) {
            av[c] = fmaf(hj, sws[j * EH + c], av[c]);
            bv[c] = fmaf(hj, swd[j * EH + c], bv[c]);
        }
    }

    float4* hp = reinterpret_cast<float4*>(hout + (size_t)n * H);
    float4* Ap = reinterpret_cast<float4*>(A    + (size_t)n * EH);
    float4* Bp = reinterpret_cast<float4*>(Bv   + (size_t)n * EH);
#pragma unroll
    for (int q = 0; q < H / 4; ++q) {
        hp[q] = make_float4(hv[4 * q + 0], hv[4 * q + 1], hv[4 * q + 2], hv[4 * q + 3]);
        Ap[q] = make_float4(av[4 * q + 0], av[4 * q + 1], av[4 * q + 2], av[4 * q + 3]);
        Bp[q] = make_float4(bv[4 * q + 0], bv[4 * q + 1], bv[4 * q + 2], bv[4 * q + 3]);
    }
}

// ---------------------------------------------------------------------------
// Edge MLP (factorized): t = A[s]+Bv[d]+ea@eW1[64:67]; relu; out = t@eW2+eb2
// ---------------------------------------------------------------------------
__global__ void edge_mlp_lite_kernel(const int* __restrict__ ei, const float* __restrict__ ea,
                                     const float* __restrict__ A, const float* __restrict__ Bv,
                                     const float* __restrict__ ew1, const float* __restrict__ eb2,
                                     const float* __restrict__ w2,
                                     float* __restrict__ out) {
    __shared__ float swe[EIN * EH];   // rows 64..66 of ew1
    __shared__ float sw2[EH * EOUT];
    __shared__ float sb2[EOUT];
    for (int i = threadIdx.x; i < EIN * EH; i += blockDim.x) swe[i] = ew1[2 * H * EH + i];
    for (int i = threadIdx.x; i < EH * EOUT; i += blockDim.x) sw2[i] = w2[i];
    for (int i = threadIdx.x; i < EOUT; i += blockDim.x) sb2[i] = eb2[i];
    __syncthreads();

    int e = blockIdx.x * blockDim.x + threadIdx.x;
    if (e >= EE) return;

    int s = ei[e];
    int d = ei[EE + e];

    float a0 = ea[(size_t)e * EIN + 0];
    float a1 = ea[(size_t)e * EIN + 1];
    float a2 = ea[(size_t)e * EIN + 2];

    const float4* Ap = reinterpret_cast<const float4*>(A  + (size_t)s * EH);
    const float4* Bp = reinterpret_cast<const float4*>(Bv + (size_t)d * EH);

    float t[EH];
#pragma unroll
    for (int q = 0; q < EH / 4; ++q) {
        float4 va = Ap[q];
        float4 vb = Bp[q];
        t[4 * q + 0] = va.x + vb.x;
        t[4 * q + 1] = va.y + vb.y;
        t[4 * q + 2] = va.z + vb.z;
        t[4 * q + 3] = va.w + vb.w;
    }
#pragma unroll
    for (int c = 0; c < EH; ++c) {
        t[c] = fmaf(a0, swe[0 * EH + c], t[c]);
        t[c] = fmaf(a1, swe[1 * EH + c], t[c]);
        t[c] = fmaf(a2, swe[2 * EH + c], t[c]);
    }

    float o[EOUT];
#pragma unroll
    for (int c = 0; c < EOUT; ++c) o[c] = sb2[c];
#pragma unroll
    for (int j = 0; j < EH; ++j) {
        float r = fmaxf(t[j], 0.0f);
#pragma unroll
        for (int c = 0; c < EOUT; ++c) o[c] = fmaf(r, sw2[j * EOUT + c], o[c]);
    }

    float4* op = reinterpret_cast<float4*>(out + (size_t)e * EOUT);
#pragma unroll
    for (int q = 0; q < EOUT / 4; ++q)
        op[q] = make_float4(o[4 * q + 0], o[4 * q + 1], o[4 * q + 2], o[4 * q + 3]);
}

// ---------------------------------------------------------------------------
extern "C" void kernel_launch(void* const* d_in, const int* in_sizes, int n_in,
                              void* d_out, int out_size, void* d_ws, size_t ws_size,
                              hipStream_t stream) {
    const float* x   = (const float*)d_in[0];
    const int*   ei  = (const int*)  d_in[1];
    const float* ea  = (const float*)d_in[2];
    const float* nw1 = (const float*)d_in[3];
    const float* nb1 = (const float*)d_in[4];
    const float* nw2 = (const float*)d_in[5];
    const float* nb2 = (const float*)d_in[6];
    const float* gw1 = (const float*)d_in[7];
    const float* gb1 = (const float*)d_in[8];
    const float* gw2 = (const float*)d_in[9];
    const float* gb2 = (const float*)d_in[10];
    const float* ew1 = (const float*)d_in[11];
    const float* eb1 = (const float*)d_in[12];
    const float* ew2 = (const float*)d_in[13];
    const float* eb2 = (const float*)d_in[14];

    float* h_out = (float*)d_out;                       // [N, H]
    float* e_out = (float*)d_out + (size_t)NN * H;      // [E, EOUT]

    // workspace layout
    float* ws_f   = (float*)d_ws;
    float* hws    = ws_f;                                // [N, H]
    float* acc    = hws  + (size_t)NN * H;               // [N, H]
    float* A      = acc  + (size_t)NN * H;               // [N, EH]
    float* Bv     = A    + (size_t)NN * EH;              // [N, EH]
    float* dis    = Bv   + (size_t)NN * EH;              // [N]
    int*   cnt    = (int*)(dis + NN);                    // [N]
    int*   cursor = cnt + NN;                            // [N]
    int*   ptr    = cursor + NN;                         // [N+1]
    int*   adj    = ptr + (NN + 1);                      // [E]

    const int B = 256;
    dim3 blk(B);

    // CSR build (also produces dis via degree)
    csr_init_kernel<<<(NN + B - 1) / B, blk, 0, stream>>>(cnt, cursor);
    csr_hist_kernel<<<(EE + B - 1) / B, blk, 0, stream>>>(ei, cnt);
    csr_scan_kernel<<<1, 1024, 0, stream>>>(cnt, ptr, dis);
    csr_fill_kernel<<<(EE + B - 1) / B, blk, 0, stream>>>(ei, ptr, cursor, adj);

    const int NODES_PER_BLK = B / 32;
    int gather_grid = (NN + NODES_PER_BLK - 1) / NODES_PER_BLK;

    // layer 1 (node encoder fused with hws1 = dis * h_enc @ gW1)
    node_hws1_kernel<<<(NN + B - 1) / B, blk, 0, stream>>>(x, nw1, nb1, nw2, nb2, gw1, dis, hws);
    gcn_gather_kernel<<<gather_grid, blk, 0, stream>>>(ptr, adj, hws, dis, acc);

    // layer 2
    fin_hws2_kernel<<<(NN + B - 1) / B, blk, 0, stream>>>(gb1, gw2, dis, acc, hws);
    gcn_gather_kernel<<<gather_grid, blk, 0, stream>>>(ptr, adj, hws, dis, acc);

    // fin of layer 2 fused with edge-MLP per-node precompute
    fin_ab_kernel<<<(NN + B - 1) / B, blk, 0, stream>>>(acc, gb2, ew1, eb1, h_out, A, Bv);

    // factorized edge MLP
    edge_mlp_lite_kernel<<<(EE + B - 1) / B, blk, 0, stream>>>(ei, ea, A, Bv, ew1, eb2, ew2, e_out);
}

// Round 8
// 687.587 us; speedup vs baseline: 1.3006x; 1.3006x over previous
//
#include <hip/hip_runtime.h>
#include <hip/hip_bf16.h>

#define NN 100000
#define EE 1600000
#define H  32
#define EIN 3
#define EH 32
#define EOUT 32

#define SCAN_CHUNK 1024                       // elements per block in scan
#define SCAN_NBLK  ((NN + SCAN_CHUNK - 1) / SCAN_CHUNK)   // 98

// ---------------------------------------------------------------------------
// CSR build: zero -> histogram(dst) -> 3-kernel parallel scan -> fill adj
// ---------------------------------------------------------------------------
__global__ void csr_init_kernel(int* __restrict__ cnt, int* __restrict__ cursor) {
    int i = blockIdx.x * blockDim.x + threadIdx.x;
    if (i < NN) { cnt[i] = 0; cursor[i] = 0; }
}

__global__ void csr_hist_kernel(const int* __restrict__ ei, int* __restrict__ cnt) {
    int e = blockIdx.x * blockDim.x + threadIdx.x;
    if (e < EE) atomicAdd(&cnt[ei[EE + e]], 1);
}

// per-block sums of cnt (1024 elems / block, 256 threads x 4)
__global__ void scan_blocksum_kernel(const int* __restrict__ cnt, int* __restrict__ bsum) {
    __shared__ int red[256];
    int base = blockIdx.x * SCAN_CHUNK + threadIdx.x * 4;
    int s = 0;
#pragma unroll
    for (int k = 0; k < 4; ++k) {
        int i = base + k;
        if (i < NN) s += cnt[i];
    }
    red[threadIdx.x] = s;
    __syncthreads();
    for (int off = 128; off > 0; off >>= 1) {
        if (threadIdx.x < off) red[threadIdx.x] += red[threadIdx.x + off];
        __syncthreads();
    }
    if (threadIdx.x == 0) bsum[blockIdx.x] = red[0];
}

// exclusive scan of the 98 block sums (single tiny block)
__global__ void scan_boff_kernel(const int* __restrict__ bsum, int* __restrict__ boff) {
    __shared__ int sh[128];
    int tid = threadIdx.x;
    sh[tid] = (tid < SCAN_NBLK) ? bsum[tid] : 0;
    __syncthreads();
    for (int off = 1; off < 128; off <<= 1) {
        int v = (tid >= off) ? sh[tid - off] : 0;
        __syncthreads();
        sh[tid] += v;
        __syncthreads();
    }
    if (tid < SCAN_NBLK) boff[tid] = sh[tid] - bsum[tid];   // exclusive
}

// in-block exclusive scan + block offset -> ptr; dis = 1/sqrt(deg+1)
__global__ void scan_write_kernel(const int* __restrict__ cnt, const int* __restrict__ boff,
                                  int* __restrict__ ptr, float* __restrict__ dis) {
    __shared__ int sh[256];
    int tid = threadIdx.x;
    int base = blockIdx.x * SCAN_CHUNK + tid * 4;

    int v[4];
    int s = 0;
#pragma unroll
    for (int k = 0; k < 4; ++k) {
        int i = base + k;
        v[k] = (i < NN) ? cnt[i] : 0;
        s += v[k];
    }
    sh[tid] = s;
    __syncthreads();
    for (int off = 1; off < 256; off <<= 1) {
        int t = (tid >= off) ? sh[tid - off] : 0;
        __syncthreads();
        sh[tid] += t;
        __syncthreads();
    }
    int prefix = boff[blockIdx.x] + sh[tid] - s;   // exclusive prefix for this thread

#pragma unroll
    for (int k = 0; k < 4; ++k) {
        int i = base + k;
        if (i < NN) {
            ptr[i] = prefix;
            prefix += v[k];
            dis[i] = 1.0f / sqrtf((float)(v[k] + 1));
        }
    }
    if (blockIdx.x == 0 && tid == 0) ptr[NN] = EE;   // total is known analytically
}

__global__ void csr_fill_kernel(const int* __restrict__ ei, const int* __restrict__ ptr,
                                int* __restrict__ cursor, int* __restrict__ adj) {
    int e = blockIdx.x * blockDim.x + threadIdx.x;
    if (e >= EE) return;
    int s = ei[e];
    int d = ei[EE + e];
    int pos = ptr[d] + atomicAdd(&cursor[d], 1);
    adj[pos] = s;
}

// ---------------------------------------------------------------------------
// Fused: node encoder MLP -> hws = dis[n] * (h_enc @ gW1)
// ---------------------------------------------------------------------------
__global__ void node_hws1_kernel(const float* __restrict__ x,
                                 const float* __restrict__ w1, const float* __restrict__ b1,
                                 const float* __restrict__ w2, const float* __restrict__ b2,
                                 const float* __restrict__ gW, const float* __restrict__ dis,
                                 float* __restrict__ hws) {
    __shared__ float sw1[2 * H];
    __shared__ float sb1[H];
    __shared__ float sw2[H * H];
    __shared__ float sb2[H];
    __shared__ float sgw[H * H];
    for (int i = threadIdx.x; i < 2 * H; i += blockDim.x) sw1[i] = w1[i];
    for (int i = threadIdx.x; i < H; i += blockDim.x) { sb1[i] = b1[i]; sb2[i] = b2[i]; }
    for (int i = threadIdx.x; i < H * H; i += blockDim.x) { sw2[i] = w2[i]; sgw[i] = gW[i]; }
    __syncthreads();

    int n = blockIdx.x * blockDim.x + threadIdx.x;
    if (n >= NN) return;

    float x0 = x[2 * n + 0];
    float x1 = x[2 * n + 1];

    float t[H];
#pragma unroll
    for (int j = 0; j < H; ++j)
        t[j] = fmaxf(fmaf(x1, sw1[H + j], fmaf(x0, sw1[j], sb1[j])), 0.0f);

    float henc[H];
#pragma unroll
    for (int c = 0; c < H; ++c) henc[c] = sb2[c];
#pragma unroll
    for (int j = 0; j < H; ++j) {
        float tj = t[j];
#pragma unroll
        for (int c = 0; c < H; ++c) henc[c] = fmaf(tj, sw2[j * H + c], henc[c]);
    }

    float o[H];
#pragma unroll
    for (int c = 0; c < H; ++c) o[c] = 0.0f;
#pragma unroll
    for (int j = 0; j < H; ++j) {
        float hj = henc[j];
#pragma unroll
        for (int c = 0; c < H; ++c) o[c] = fmaf(hj, sgw[j * H + c], o[c]);
    }

    float d = dis[n];
    float4* hp = reinterpret_cast<float4*>(hws + (size_t)n * H);
#pragma unroll
    for (int q = 0; q < H / 4; ++q)
        hp[q] = make_float4(o[4 * q + 0] * d, o[4 * q + 1] * d, o[4 * q + 2] * d, o[4 * q + 3] * d);
}

// ---------------------------------------------------------------------------
// Gather: acc[n][c] = dis[n] * (hws[n][c] + sum_{in-edges} hws[src][c])
// ---------------------------------------------------------------------------
__global__ void gcn_gather_kernel(const int* __restrict__ ptr, const int* __restrict__ adj,
                                  const float* __restrict__ hws, const float* __restrict__ dis,
                                  float* __restrict__ acc) {
    int lane = threadIdx.x & 31;
    int g = threadIdx.x >> 5;
    int n = blockIdx.x * (blockDim.x >> 5) + g;
    if (n >= NN) return;

    int rs = ptr[n];
    int re = ptr[n + 1];

    float a0 = hws[(size_t)n * H + lane];   // self-loop term
    float a1 = 0.0f;

    for (int base = rs; base < re; base += 32) {
        int cnt = re - base; if (cnt > 32) cnt = 32;
        int sv = adj[base + ((lane < cnt) ? lane : (cnt - 1))];
#pragma unroll 4
        for (int k = 0; k < cnt; k += 2) {
            int s0 = __shfl(sv, k, 32);
            a0 += hws[(size_t)s0 * H + lane];
            if (k + 1 < cnt) {
                int s1 = __shfl(sv, k + 1, 32);
                a1 += hws[(size_t)s1 * H + lane];
            }
        }
    }
    acc[(size_t)n * H + lane] = dis[n] * (a0 + a1);
}

// ---------------------------------------------------------------------------
// Fused: h1 = relu(acc + b_prev); hws = dis[n] * (h1 @ gW2)
// ---------------------------------------------------------------------------
__global__ void fin_hws2_kernel(const float* __restrict__ bprev, const float* __restrict__ gW,
                                const float* __restrict__ dis,
                                const float* __restrict__ acc, float* __restrict__ hws) {
    __shared__ float sgw[H * H];
    __shared__ float sb[H];
    for (int i = threadIdx.x; i < H * H; i += blockDim.x) sgw[i] = gW[i];
    for (int i = threadIdx.x; i < H; i += blockDim.x) sb[i] = bprev[i];
    __syncthreads();

    int n = blockIdx.x * blockDim.x + threadIdx.x;
    if (n >= NN) return;

    float hv[H];
    const float4* ap = reinterpret_cast<const float4*>(acc + (size_t)n * H);
#pragma unroll
    for (int q = 0; q < H / 4; ++q) {
        float4 v = ap[q];
        hv[4 * q + 0] = fmaxf(v.x + sb[4 * q + 0], 0.0f);
        hv[4 * q + 1] = fmaxf(v.y + sb[4 * q + 1], 0.0f);
        hv[4 * q + 2] = fmaxf(v.z + sb[4 * q + 2], 0.0f);
        hv[4 * q + 3] = fmaxf(v.w + sb[4 * q + 3], 0.0f);
    }

    float o[H];
#pragma unroll
    for (int c = 0; c < H; ++c) o[c] = 0.0f;
#pragma unroll
    for (int j = 0; j < H; ++j) {
        float hj = hv[j];
#pragma unroll
        for (int c = 0; c < H; ++c) o[c] = fmaf(hj, sgw[j * H + c], o[c]);
    }

    float d = dis[n];
    float4* hp = reinterpret_cast<float4*>(hws + (size_t)n * H);
#pragma unroll
    for (int q = 0; q < H / 4; ++q)
        hp[q] = make_float4(o[4 * q + 0] * d, o[4 * q + 1] * d, o[4 * q + 2] * d, o[4 * q + 3] * d);
}

// ---------------------------------------------------------------------------
// Fused: h = relu(acc + gb2) -> d_out ; A = h@eW1[0:32]+eb1 ; Bv = h@eW1[32:64]
// ---------------------------------------------------------------------------
__global__ void fin_ab_kernel(const float* __restrict__ acc, const float* __restrict__ gb,
                              const float* __restrict__ ew1, const float* __restrict__ eb1,
                              float* __restrict__ hout,
                              float* __restrict__ A, float* __restrict__ Bv) {
    __shared__ float sws[H * EH];   // rows 0..31 of ew1
    __shared__ float swd[H * EH];   // rows 32..63 of ew1
    __shared__ float sgb[H];
    __shared__ float seb[EH];
    for (int i = threadIdx.x; i < H * EH; i += blockDim.x) {
        sws[i] = ew1[i];
        swd[i] = ew1[H * EH + i];
    }
    for (int i = threadIdx.x; i < H; i += blockDim.x) sgb[i] = gb[i];
    for (int i = threadIdx.x; i < EH; i += blockDim.x) seb[i] = eb1[i];
    __syncthreads();

    int n = blockIdx.x * blockDim.x + threadIdx.x;
    if (n >= NN) return;

    float hv[H];
    const float4* ap = reinterpret_cast<const float4*>(acc + (size_t)n * H);
#pragma unroll
    for (int q = 0; q < H / 4; ++q) {
        float4 v = ap[q];
        hv[4 * q + 0] = fmaxf(v.x + sgb[4 * q + 0], 0.0f);
        hv[4 * q + 1] = fmaxf(v.y + sgb[4 * q + 1], 0.0f);
        hv[4 * q + 2] = fmaxf(v.z + sgb[4 * q + 2], 0.0f);
        hv[4 * q + 3] = fmaxf(v.w + sgb[4 * q + 3], 0.0f);
    }

    float av[EH], bv[EH];
#pragma unroll
    for (int c = 0; c < EH; ++c) { av[c] = seb[c]; bv[c] = 0.0f; }
#pragma unroll
    for (int j = 0; j < H; ++j) {
        float hj = hv[j];
#pragma unroll
        for (int c = 0; c < EH; ++c) {
            av[c] = fmaf(hj, sws[j * EH + c], av[c]);
            bv[c] = fmaf(hj, swd[j * EH + c], bv[c]);
        }
    }

    float4* hp = reinterpret_cast<float4*>(hout + (size_t)n * H);
    float4* Ap = reinterpret_cast<float4*>(A    + (size_t)n * EH);
    float4* Bp = reinterpret_cast<float4*>(Bv   + (size_t)n * EH);
#pragma unroll
    for (int q = 0; q < H / 4; ++q) {
        hp[q] = make_float4(hv[4 * q + 0], hv[4 * q + 1], hv[4 * q + 2], hv[4 * q + 3]);
        Ap[q] = make_float4(av[4 * q + 0], av[4 * q + 1], av[4 * q + 2], av[4 * q + 3]);
        Bp[q] = make_float4(bv[4 * q + 0], bv[4 * q + 1], bv[4 * q + 2], bv[4 * q + 3]);
    }
}

// ---------------------------------------------------------------------------
// Edge MLP (factorized): t = A[s]+Bv[d]+ea@eW1[64:67]; relu; out = t@eW2+eb2
// ---------------------------------------------------------------------------
__global__ void edge_mlp_lite_kernel(const int* __restrict__ ei, const float* __restrict__ ea,
                                     const float* __restrict__ A, const float* __restrict__ Bv,
                                     const float* __restrict__ ew1, const float* __restrict__ eb2,
                                     const float* __restrict__ w2,
                                     float* __restrict__ out) {
    __shared__ float swe[EIN * EH];   // rows 64..66 of ew1
    __shared__ float sw2[EH * EOUT];
    __shared__ float sb2[EOUT];
    for (int i = threadIdx.x; i < EIN * EH; i += blockDim.x) swe[i] = ew1[2 * H * EH + i];
    for (int i = threadIdx.x; i < EH * EOUT; i += blockDim.x) sw2[i] = w2[i];
    for (int i = threadIdx.x; i < EOUT; i += blockDim.x) sb2[i] = eb2[i];
    __syncthreads();

    int e = blockIdx.x * blockDim.x + threadIdx.x;
    if (e >= EE) return;

    int s = ei[e];
    int d = ei[EE + e];

    float a0 = ea[(size_t)e * EIN + 0];
    float a1 = ea[(size_t)e * EIN + 1];
    float a2 = ea[(size_t)e * EIN + 2];

    const float4* Ap = reinterpret_cast<const float4*>(A  + (size_t)s * EH);
    const float4* Bp = reinterpret_cast<const float4*>(Bv + (size_t)d * EH);

    float t[EH];
#pragma unroll
    for (int q = 0; q < EH / 4; ++q) {
        float4 va = Ap[q];
        float4 vb = Bp[q];
        t[4 * q + 0] = va.x + vb.x;
        t[4 * q + 1] = va.y + vb.y;
        t[4 * q + 2] = va.z + vb.z;
        t[4 * q + 3] = va.w + vb.w;
    }
#pragma unroll
    for (int c = 0; c < EH; ++c) {
        t[c] = fmaf(a0, swe[0 * EH + c], t[c]);
        t[c] = fmaf(a1, swe[1 * EH + c], t[c]);
        t[c] = fmaf(a2, swe[2 * EH + c], t[c]);
    }

    float o[EOUT];
#pragma unroll
    for (int c = 0; c < EOUT; ++c) o[c] = sb2[c];
#pragma unroll
    for (int j = 0; j < EH; ++j) {
        float r = fmaxf(t[j], 0.0f);
#pragma unroll
        for (int c = 0; c < EOUT; ++c) o[c] = fmaf(r, sw2[j * EOUT + c], o[c]);
    }

    float4* op = reinterpret_cast<float4*>(out + (size_t)e * EOUT);
#pragma unroll
    for (int q = 0; q < EOUT / 4; ++q)
        op[q] = make_float4(o[4 * q + 0], o[4 * q + 1], o[4 * q + 2], o[4 * q + 3]);
}

// ---------------------------------------------------------------------------
extern "C" void kernel_launch(void* const* d_in, const int* in_sizes, int n_in,
                              void* d_out, int out_size, void* d_ws, size_t ws_size,
                              hipStream_t stream) {
    const float* x   = (const float*)d_in[0];
    const int*   ei  = (const int*)  d_in[1];
    const float* ea  = (const float*)d_in[2];
    const float* nw1 = (const float*)d_in[3];
    const float* nb1 = (const float*)d_in[4];
    const float* nw2 = (const float*)d_in[5];
    const float* nb2 = (const float*)d_in[6];
    const float* gw1 = (const float*)d_in[7];
    const float* gb1 = (const float*)d_in[8];
    const float* gw2 = (const float*)d_in[9];
    const float* gb2 = (const float*)d_in[10];
    const float* ew1 = (const float*)d_in[11];
    const float* eb1 = (const float*)d_in[12];
    const float* ew2 = (const float*)d_in[13];
    const float* eb2 = (const float*)d_in[14];

    float* h_out = (float*)d_out;                       // [N, H]
    float* e_out = (float*)d_out + (size_t)NN * H;      // [E, EOUT]

    // workspace layout
    float* ws_f   = (float*)d_ws;
    float* hws    = ws_f;                                // [N, H]
    float* acc    = hws  + (size_t)NN * H;               // [N, H]
    float* A      = acc  + (size_t)NN * H;               // [N, EH]
    float* Bv     = A    + (size_t)NN * EH;              // [N, EH]
    float* dis    = Bv   + (size_t)NN * EH;              // [N]
    int*   cnt    = (int*)(dis + NN);                    // [N]
    int*   cursor = cnt + NN;                            // [N]
    int*   ptr    = cursor + NN;                         // [N+1]
    int*   bsum   = ptr + (NN + 1);                      // [98]
    int*   boff   = bsum + SCAN_NBLK;                    // [98]
    int*   adj    = boff + SCAN_NBLK;                    // [E]

    const int B = 256;
    dim3 blk(B);

    // CSR build (also produces dis via degree)
    csr_init_kernel<<<(NN + B - 1) / B, blk, 0, stream>>>(cnt, cursor);
    csr_hist_kernel<<<(EE + B - 1) / B, blk, 0, stream>>>(ei, cnt);
    scan_blocksum_kernel<<<SCAN_NBLK, blk, 0, stream>>>(cnt, bsum);
    scan_boff_kernel<<<1, 128, 0, stream>>>(bsum, boff);
    scan_write_kernel<<<SCAN_NBLK, blk, 0, stream>>>(cnt, boff, ptr, dis);
    csr_fill_kernel<<<(EE + B - 1) / B, blk, 0, stream>>>(ei, ptr, cursor, adj);

    const int NODES_PER_BLK = B / 32;
    int gather_grid = (NN + NODES_PER_BLK - 1) / NODES_PER_BLK;

    // layer 1 (node encoder fused with hws1 = dis * h_enc @ gW1)
    node_hws1_kernel<<<(NN + B - 1) / B, blk, 0, stream>>>(x, nw1, nb1, nw2, nb2, gw1, dis, hws);
    gcn_gather_kernel<<<gather_grid, blk, 0, stream>>>(ptr, adj, hws, dis, acc);

    // layer 2
    fin_hws2_kernel<<<(NN + B - 1) / B, blk, 0, stream>>>(gb1, gw2, dis, acc, hws);
    gcn_gather_kernel<<<gather_grid, blk, 0, stream>>>(ptr, adj, hws, dis, acc);

    // fin of layer 2 fused with edge-MLP per-node precompute
    fin_ab_kernel<<<(NN + B - 1) / B, blk, 0, stream>>>(acc, gb2, ew1, eb1, h_out, A, Bv);

    // factorized edge MLP
    edge_mlp_lite_kernel<<<(EE + B - 1) / B, blk, 0, stream>>>(ei, ea, A, Bv, ew1, eb2, ew2, e_out);
}